// Round 9
// baseline (369.488 us; speedup 1.0000x reference)
//
#include <hip/hip_runtime.h>

#define N_VOX 100000
#define KVOL 27
#define MPAIR 50000
#define CIN 64
#define COUT 64
#define TPW 8
#define NTILES 3125          // 50000 / 16, exact

typedef __attribute__((ext_vector_type(8))) short bf16x8;   // 8 bf16 = 4 VGPRs
typedef __attribute__((ext_vector_type(4))) float f32x4;
typedef __attribute__((ext_vector_type(4))) unsigned short u16x4;

__device__ inline unsigned short f2bf(float f) {  // RNE f32 -> bf16
    union { float f; unsigned u; } v; v.f = f;
    return (unsigned short)((v.u + 0x7FFFu + ((v.u >> 16) & 1u)) >> 16);
}

// out[n][c] = bias[c]  (folds bias; clears the 0xAA poison)
__global__ void spconv_init_bias(const float* __restrict__ bias,
                                 float* __restrict__ out, int total) {
    int i = blockIdx.x * blockDim.x + threadIdx.x;
    if (i < total) out[i] = bias[i & (COUT - 1)];
}

// x (f32) -> xbf (bf16), 4 elems/thread
__global__ void spconv_x_to_bf16(const float* __restrict__ x,
                                 unsigned short* __restrict__ xbf, int n4) {
    int i = blockIdx.x * blockDim.x + threadIdx.x;
    if (i >= n4) return;
    f32x4 v = ((const f32x4*)x)[i];
    u16x4 o; o.x = f2bf(v.x); o.y = f2bf(v.y); o.z = f2bf(v.z); o.w = f2bf(v.w);
    ((u16x4*)xbf)[i] = o;
}

// Software-pipelined main kernel: bf16 x gather (128B rows), prefetch depth 1,
// all in_map indices preloaded, f32 atomic scatter.
__global__ __launch_bounds__(256) void spconv_mfma_pipe(
    const unsigned short* __restrict__ xbf,
    const float* __restrict__ kern,
    const int*   __restrict__ in_map,
    const int*   __restrict__ out_map,
    float*       __restrict__ out)
{
    const int lane = threadIdx.x & 63;
    const int wave = threadIdx.x >> 6;
    const int k    = blockIdx.y;
    const int g    = lane >> 4;
    const int r16  = lane & 15;

    // ---- B fragments (once per wave): frag[s][t] elem j = W[k][s*32+g*8+j][t*16+r16]
    bf16x8 bfrag[2][4];
    {
        const float* wp = kern + (size_t)k * CIN * COUT;
        #pragma unroll
        for (int s = 0; s < 2; ++s)
            #pragma unroll
            for (int t = 0; t < 4; ++t) {
                const float* q = wp + (s * 32 + g * 8) * COUT + t * 16 + r16;
                bf16x8 f;
                #pragma unroll
                for (int j = 0; j < 8; ++j) f[j] = (short)f2bf(q[j * COUT]);
                bfrag[s][t] = f;
            }
    }

    const int tile0 = (blockIdx.x * 4 + wave) * TPW;
    const int base0 = k * MPAIR;

    // ---- preload ALL in-row indices for this wave's 8 tiles (removes the
    // in_map->gather round trip from the steady-state chain)
    int inrow[TPW];
    #pragma unroll
    for (int t = 0; t < TPW; ++t) {
        int tl = tile0 + t; tl = tl < NTILES ? tl : NTILES - 1;
        inrow[t] = in_map[base0 + tl * 16 + r16];
    }

    // ---- prefetch tile 0: A-frags + out rows
    bf16x8 acur[2], anxt[2];
    #pragma unroll
    for (int s = 0; s < 2; ++s)
        acur[s] = *(const bf16x8*)(xbf + (size_t)inrow[0] * CIN + g * 8 + s * 32);

    int orow_c[4], orow_n[4];
    {
        int tl = tile0 < NTILES ? tile0 : NTILES - 1;
        #pragma unroll
        for (int r = 0; r < 4; ++r) orow_c[r] = out_map[base0 + tl * 16 + g * 4 + r];
    }

    #pragma unroll
    for (int t = 0; t < TPW; ++t) {
        // prefetch tile t+1 while computing tile t
        if (t + 1 < TPW) {
            int tl = tile0 + t + 1; tl = tl < NTILES ? tl : NTILES - 1;
            #pragma unroll
            for (int s = 0; s < 2; ++s)
                anxt[s] = *(const bf16x8*)(xbf + (size_t)inrow[t + 1] * CIN + g * 8 + s * 32);
            #pragma unroll
            for (int r = 0; r < 4; ++r) orow_n[r] = out_map[base0 + tl * 16 + g * 4 + r];
        }

        if (tile0 + t < NTILES) {                 // wave-uniform
            f32x4 acc[4] = {{0.f,0.f,0.f,0.f},{0.f,0.f,0.f,0.f},
                            {0.f,0.f,0.f,0.f},{0.f,0.f,0.f,0.f}};
            #pragma unroll
            for (int q = 0; q < 4; ++q) {
                acc[q] = __builtin_amdgcn_mfma_f32_16x16x32_bf16(acur[0], bfrag[0][q], acc[q], 0, 0, 0);
                acc[q] = __builtin_amdgcn_mfma_f32_16x16x32_bf16(acur[1], bfrag[1][q], acc[q], 0, 0, 0);
            }
            #pragma unroll
            for (int r = 0; r < 4; ++r) {
                float* op = out + (size_t)orow_c[r] * COUT + r16;
                #pragma unroll
                for (int q = 0; q < 4; ++q)
                    atomicAdd(op + q * 16, acc[q][r]);
            }
        }

        // static rotate (fully unrolled -> compile-time indices, no scratch)
        acur[0] = anxt[0]; acur[1] = anxt[1];
        #pragma unroll
        for (int r = 0; r < 4; ++r) orow_c[r] = orow_n[r];
    }
}

// ---------- fallback (ws too small): proven r6 path, f32 x + cvt ----------
__global__ __launch_bounds__(256) void spconv_mfma_f32at(
    const float* __restrict__ x,
    const float* __restrict__ kern,
    const int*   __restrict__ in_map,
    const int*   __restrict__ out_map,
    float*       __restrict__ out)
{
    const int lane = threadIdx.x & 63;
    const int wave = threadIdx.x >> 6;
    const int k    = blockIdx.y;
    const int g    = lane >> 4;
    const int r16  = lane & 15;

    bf16x8 bfrag[2][4];
    {
        const float* wp = kern + (size_t)k * CIN * COUT;
        #pragma unroll
        for (int s = 0; s < 2; ++s)
            #pragma unroll
            for (int t = 0; t < 4; ++t) {
                const float* q = wp + (s * 32 + g * 8) * COUT + t * 16 + r16;
                bf16x8 f;
                #pragma unroll
                for (int j = 0; j < 8; ++j) f[j] = (short)f2bf(q[j * COUT]);
                bfrag[s][t] = f;
            }
    }

    for (int it = 0; it < TPW; ++it) {
        int tile = (blockIdx.x * 4 + wave) * TPW + it;
        if (tile >= NTILES) break;
        int base = k * MPAIR + tile * 16;

        int im = in_map[base + r16];
        bf16x8 afrag[2];
        const float* xp = x + (size_t)im * CIN + g * 8;
        #pragma unroll
        for (int s = 0; s < 2; ++s) {
            f32x4 v0 = *(const f32x4*)(xp + s * 32);
            f32x4 v1 = *(const f32x4*)(xp + s * 32 + 4);
            bf16x8 f;
            f[0] = (short)f2bf(v0[0]); f[1] = (short)f2bf(v0[1]);
            f[2] = (short)f2bf(v0[2]); f[3] = (short)f2bf(v0[3]);
            f[4] = (short)f2bf(v1[0]); f[5] = (short)f2bf(v1[1]);
            f[6] = (short)f2bf(v1[2]); f[7] = (short)f2bf(v1[3]);
            afrag[s] = f;
        }

        f32x4 acc[4] = {{0.f,0.f,0.f,0.f},{0.f,0.f,0.f,0.f},
                        {0.f,0.f,0.f,0.f},{0.f,0.f,0.f,0.f}};
        #pragma unroll
        for (int q = 0; q < 4; ++q) {
            acc[q] = __builtin_amdgcn_mfma_f32_16x16x32_bf16(afrag[0], bfrag[0][q], acc[q], 0, 0, 0);
            acc[q] = __builtin_amdgcn_mfma_f32_16x16x32_bf16(afrag[1], bfrag[1][q], acc[q], 0, 0, 0);
        }

        int orow[4];
        #pragma unroll
        for (int r = 0; r < 4; ++r) orow[r] = out_map[base + g * 4 + r];
        #pragma unroll
        for (int r = 0; r < 4; ++r) {
            float* op = out + (size_t)orow[r] * COUT + r16;
            #pragma unroll
            for (int q = 0; q < 4; ++q)
                atomicAdd(op + q * 16, acc[q][r]);
        }
    }
}

extern "C" void kernel_launch(void* const* d_in, const int* in_sizes, int n_in,
                              void* d_out, int out_size, void* d_ws, size_t ws_size,
                              hipStream_t stream) {
    const float* x       = (const float*)d_in[0];
    const float* kern    = (const float*)d_in[1];
    const float* bias    = (const float*)d_in[2];
    const int*   in_map  = (const int*)d_in[3];
    const int*   out_map = (const int*)d_in[4];
    float*       out     = (float*)d_out;

    dim3 grid((NTILES + 4 * TPW - 1) / (4 * TPW), KVOL);   // 98 x 27

    int total = N_VOX * COUT;
    spconv_init_bias<<<(total + 255) / 256, 256, 0, stream>>>(bias, out, total);

    const size_t ws_need = (size_t)N_VOX * CIN * sizeof(unsigned short);  // 12.8 MB
    if (ws_size >= ws_need) {
        unsigned short* xbf = (unsigned short*)d_ws;
        int n4 = N_VOX * CIN / 4;
        spconv_x_to_bf16<<<(n4 + 255) / 256, 256, 0, stream>>>(x, xbf, n4);
        spconv_mfma_pipe<<<grid, 256, 0, stream>>>(xbf, kern, in_map, out_map, out);
    } else {
        spconv_mfma_f32at<<<grid, 256, 0, stream>>>(x, kern, in_map, out_map, out);
    }
}